// Round 5
// baseline (3754.921 us; speedup 1.0000x reference)
//
#include <hip/hip_runtime.h>
#include <hip/hip_bf16.h>
#include <stdint.h>

#define TT   512
#define BB   128
#define DIN  256
#define DH   512
#define DOUT 256
#define NV   (BB*DH)     // 65536
#define NLOG (BB*DOUT)   // 32768
#define MTOT (TT*BB)     // 65536

typedef unsigned short u16;
typedef __attribute__((ext_vector_type(8))) short bf16x8;
typedef __attribute__((ext_vector_type(4))) float f32x4;

__device__ __forceinline__ void gld_lds16(const float* g, float* l) {
    __builtin_amdgcn_global_load_lds(
        (const __attribute__((address_space(1))) void*)g,
        (__attribute__((address_space(3))) void*)l, 16, 0, 0);
}

// ========== GEMM1: CUR = X @ Win + bin, strict f32 (bitwise-np) =============
// 128x256 tile, 512 threads, 8x8/thread (acc=64 VGPR -> 4 waves/SIMD), BK=16,
// double-buffered LDS, ONE barrier per k-step. B staged via global_load_lds
// (no staging regs); A staged via one float4/thread. Per output element the
// math is unchanged: single accumulator, fmaf over k ascending (bitwise).
__global__ __launch_bounds__(512, 4) void gemm1_f32(
    const float* __restrict__ X, const float* __restrict__ Win,
    const float* __restrict__ bin, float* __restrict__ CUR)
{
    __shared__ __align__(16) float As[2][16][132];   // [buf][k][m] (+pad)
    __shared__ __align__(16) float Bs[2][16][256];   // [buf][k][n] (linear: gld_lds)
    const int bm = blockIdx.x * 128;
    const int bn = blockIdx.y * 256;
    const int t  = threadIdx.x;
    const int lane = t & 63, wid = t >> 6;        // 8 waves
    const int tx = t & 31, ty = t >> 5;           // 32(cols) x 16(rows) grid
    const int am = t >> 2, ak = t & 3;            // A staging: row am, k-quad ak
    float acc[8][8] = {};                         // [i][g*2+p]: row ty*8+i, col g*64+tx*2+p
    float4 a4r;

    // prologue: stage tile 0
    a4r = *reinterpret_cast<const float4*>(&X[(size_t)(bm+am)*DIN + ak*4]);
    As[0][ak*4+0][am] = a4r.x; As[0][ak*4+1][am] = a4r.y;
    As[0][ak*4+2][am] = a4r.z; As[0][ak*4+3][am] = a4r.w;
    gld_lds16(&Win[(size_t)(wid*2+0)*DH + bn + lane*4], &Bs[0][wid*2+0][0]);
    gld_lds16(&Win[(size_t)(wid*2+1)*DH + bn + lane*4], &Bs[0][wid*2+1][0]);
    __syncthreads();

    int nb = 0;
    for (int k0 = 0; k0 < DIN; k0 += 16) {
        const int nxt = k0 + 16;
        if (nxt < DIN) {   // issue next-tile loads early (hidden under compute)
            gld_lds16(&Win[(size_t)(nxt + wid*2+0)*DH + bn + lane*4], &Bs[nb^1][wid*2+0][0]);
            gld_lds16(&Win[(size_t)(nxt + wid*2+1)*DH + bn + lane*4], &Bs[nb^1][wid*2+1][0]);
            a4r = *reinterpret_cast<const float4*>(&X[(size_t)(bm+am)*DIN + nxt + ak*4]);
        }
        #pragma unroll
        for (int kk = 0; kk < 16; ++kk) {
            float a[8], b[8];
            float4 a0 = *reinterpret_cast<const float4*>(&As[nb][kk][ty*8]);
            float4 a1 = *reinterpret_cast<const float4*>(&As[nb][kk][ty*8+4]);
            a[0]=a0.x; a[1]=a0.y; a[2]=a0.z; a[3]=a0.w;
            a[4]=a1.x; a[5]=a1.y; a[6]=a1.z; a[7]=a1.w;
            #pragma unroll
            for (int g = 0; g < 4; ++g) {   // consecutive col-pairs: 2-way = free
                float2 bp = *reinterpret_cast<const float2*>(&Bs[nb][kk][g*64 + tx*2]);
                b[g*2+0] = bp.x; b[g*2+1] = bp.y;
            }
            #pragma unroll
            for (int i = 0; i < 8; ++i)
                #pragma unroll
                for (int j = 0; j < 8; ++j)
                    acc[i][j] = fmaf(a[i], b[j], acc[i][j]);
        }
        if (nxt < DIN) {   // transpose-write A after compute (vmcnt hidden)
            As[nb^1][ak*4+0][am] = a4r.x; As[nb^1][ak*4+1][am] = a4r.y;
            As[nb^1][ak*4+2][am] = a4r.z; As[nb^1][ak*4+3][am] = a4r.w;
        }
        __syncthreads();   // one barrier per k-step
        nb ^= 1;
    }

    #pragma unroll
    for (int i = 0; i < 8; ++i) {
        const int row = bm + ty*8 + i;
        #pragma unroll
        for (int g = 0; g < 4; ++g) {
            const int col = bn + g*64 + tx*2;
            float2 o;
            o.x = __fadd_rn(acc[i][g*2+0], bin[col+0]);
            o.y = __fadd_rn(acc[i][g*2+1], bin[col+1]);
            *reinterpret_cast<float2*>(&CUR[(size_t)row*DH + col]) = o;
        }
    }
}

// ========== scan: strict-f32 recurrence, 16-deep load pipeline ==============
__global__ __launch_bounds__(256) void scan_k(
    const float* __restrict__ CUR, const float* __restrict__ wrec,
    u16* __restrict__ SPK, unsigned int* __restrict__ cnt)
{
    const int i = blockIdx.x*256 + threadIdx.x;
    float v = 0.0f;                       // V0 = 0
    const float w = wrec[i & (DH-1)];
    int c = 0;
    float cur[16], nxt[16];
    #pragma unroll
    for (int u = 0; u < 16; ++u) cur[u] = CUR[(size_t)u*NV + i];
    for (int t0 = 0; t0 < TT; t0 += 16) {
        if (t0 + 16 < TT) {
            #pragma unroll
            for (int u = 0; u < 16; ++u) nxt[u] = CUR[(size_t)(t0+16+u)*NV + i];
        }
        u16 sp[16];
        #pragma unroll
        for (int u = 0; u < 16; ++u) {
            const bool s = v > 1.0f;      // (V-1>0) <=> V>1 exactly in f32
            sp[u] = s ? (u16)0x3F80 : (u16)0;   // bf16 1.0 / 0.0
            c += (int)s;
            float t1 = __fmul_rn(0.9f, v);
            float t2 = __fadd_rn(t1, cur[u]);
            float t3 = __fadd_rn(t2, s ? w : 0.0f);
            v = __fsub_rn(t3, s ? 1.0f : 0.0f);
        }
        #pragma unroll
        for (int u = 0; u < 16; ++u) SPK[(size_t)(t0+u)*NV + i] = sp[u];
        #pragma unroll
        for (int u = 0; u < 16; ++u) cur[u] = nxt[u];
    }
    #pragma unroll
    for (int o = 32; o > 0; o >>= 1) c += __shfl_down(c, o, 64);
    if ((threadIdx.x & 63) == 0) atomicAdd(cnt, (unsigned int)c);
}

// ========== W_head -> bf16 transposed [DOUT][DH] ============================
__global__ __launch_bounds__(256) void trsp_k(
    const float* __restrict__ Wh, u16* __restrict__ WhT)
{
    const int id = blockIdx.x*256 + threadIdx.x;   // DOUT*DH
    const int n = id >> 9, k = id & (DH-1);
    __hip_bfloat16 h = __float2bfloat16(Wh[(size_t)k*DOUT + n]);
    WhT[id] = *reinterpret_cast<u16*>(&h);
}

// ========== GEMM2: logits = SPK @ Whead + bhead, bf16 MFMA ==================
// 128x128 tile, 4 waves (2x2), BK=32, 16x16x32 MFMA, double-buffered LDS,
// one barrier per k-step. Chunk XOR-swizzle c^(srow&3) kills frag-read
// bank conflicts.
__global__ __launch_bounds__(256, 2) void gemm2_mfma(
    const u16* __restrict__ SPK, const u16* __restrict__ WhT,
    const float* __restrict__ bh, float* __restrict__ Y)
{
    __shared__ __align__(16) u16 Ab[2][128*32];
    __shared__ __align__(16) u16 Bb[2][128*32];
    const int bm = blockIdx.x * 128;
    const int bn = blockIdx.y * 128;
    const int t = threadIdx.x;
    const int lane = t & 63, wid = t >> 6;
    const int wr = wid >> 1, wc = wid & 1;
    const int srow = t >> 1, shf = t & 1;
    uint4 va[2], vb[2];
    f32x4 acc[4][4];
    #pragma unroll
    for (int m = 0; m < 4; ++m)
        #pragma unroll
        for (int n = 0; n < 4; ++n) acc[m][n] = (f32x4){0.f,0.f,0.f,0.f};

    #define G2_LOAD(k0) do { \
        _Pragma("unroll") \
        for (int q = 0; q < 2; ++q) { \
            const int c = shf*2 + q; \
            va[q] = *reinterpret_cast<const uint4*>(&SPK[(size_t)(bm+srow)*DH + (k0) + c*8]); \
            vb[q] = *reinterpret_cast<const uint4*>(&WhT[(size_t)(bn+srow)*DH + (k0) + c*8]); \
        } \
    } while (0)
    #define G2_WRITE(nb) do { \
        _Pragma("unroll") \
        for (int q = 0; q < 2; ++q) { \
            const int c = shf*2 + q; \
            *reinterpret_cast<uint4*>(&Ab[nb][srow*32 + ((c ^ (srow&3))*8)]) = va[q]; \
            *reinterpret_cast<uint4*>(&Bb[nb][srow*32 + ((c ^ (srow&3))*8)]) = vb[q]; \
        } \
    } while (0)

    G2_LOAD(0);
    G2_WRITE(0);
    __syncthreads();

    int nb = 0;
    for (int k0 = 0; k0 < DH; k0 += 32) {
        const int nxt = k0 + 32;
        if (nxt < DH) G2_LOAD(nxt);
        const int l15 = lane & 15, lc = lane >> 4;
        bf16x8 af[4], bfr[4];
        #pragma unroll
        for (int m = 0; m < 4; ++m) {
            const int r = wr*64 + m*16 + l15;
            af[m] = *reinterpret_cast<const bf16x8*>(&Ab[nb][r*32 + ((lc ^ (r&3))*8)]);
        }
        #pragma unroll
        for (int n = 0; n < 4; ++n) {
            const int r = wc*64 + n*16 + l15;
            bfr[n] = *reinterpret_cast<const bf16x8*>(&Bb[nb][r*32 + ((lc ^ (r&3))*8)]);
        }
        #pragma unroll
        for (int m = 0; m < 4; ++m)
            #pragma unroll
            for (int n = 0; n < 4; ++n)
                acc[m][n] = __builtin_amdgcn_mfma_f32_16x16x32_bf16(
                    af[m], bfr[n], acc[m][n], 0, 0, 0);
        if (nxt < DH) G2_WRITE(nb^1);
        __syncthreads();
        nb ^= 1;
    }
    // epilogue: D col = lane&15, row = (lane>>4)*4 + r
    #pragma unroll
    for (int m = 0; m < 4; ++m)
        #pragma unroll
        for (int n = 0; n < 4; ++n) {
            const int row0 = bm + wr*64 + m*16 + (lane >> 4)*4;
            const int col  = bn + wc*64 + n*16 + (lane & 15);
            const float bv = bh[col];
            #pragma unroll
            for (int r = 0; r < 4; ++r)
                Y[(size_t)(row0 + r)*DOUT + col] = acc[m][n][r] + bv;
        }
}

// ========== readout: mean over T (two-stage, deterministic) =================
__global__ __launch_bounds__(256) void readout1(
    const float* __restrict__ L, double* __restrict__ P)
{
    const int j = blockIdx.x*256 + threadIdx.x;
    const int p = blockIdx.y;
    double s = 0.0;
    for (int u = 0; u < 64; ++u)
        s += (double)L[(size_t)(p*64 + u)*NLOG + j];
    P[(size_t)p*NLOG + j] = s;
}
__global__ __launch_bounds__(256) void readout2(
    const double* __restrict__ P, float* __restrict__ R,
    const unsigned int* __restrict__ cnt, float* __restrict__ srate)
{
    const int j = blockIdx.x*256 + threadIdx.x;
    double s = 0.0;
    #pragma unroll
    for (int p = 0; p < 8; ++p) s += P[(size_t)p*NLOG + j];
    R[j] = (float)(s / (double)TT);
    if (j == 0)
        srate[0] = (float)((double)cnt[0] / ((double)TT * (double)NV));
}

// ============================================================================
extern "C" void kernel_launch(void* const* d_in, const int* in_sizes, int n_in,
                              void* d_out, int out_size, void* d_ws, size_t ws_size,
                              hipStream_t stream)
{
    const float* x     = (const float*)d_in[0];   // [512][128][256]
    const float* Win   = (const float*)d_in[1];   // [256][512]
    const float* bin   = (const float*)d_in[2];   // [512]
    const float* wrec  = (const float*)d_in[3];   // [512]
    const float* Whead = (const float*)d_in[4];   // [512][256]
    const float* bhead = (const float*)d_in[5];   // [256]

    float* out     = (float*)d_out;
    float* readout = out;                           // 32768
    float* logits  = out + NLOG;                    // 512*32768
    float* srate   = out + NLOG + (size_t)TT*NLOG;  // 1

    char* w = (char*)d_ws;
    size_t off = 0;
    float* CUR = (float*)(w + off);  off += (size_t)TT*NV*4;      // 128 MB
    u16*   SPK = (u16*)  (w + off);  off += (size_t)TT*NV*2;      //  64 MB
    u16*   WhT = (u16*)  (w + off);  off += (size_t)DOUT*DH*2;    // 256 KB
    double* P  = (double*)(w + off); off += (size_t)8*NLOG*8;     //   2 MB
    unsigned int* cnt = (unsigned int*)(w + off);

    hipMemsetAsync(cnt, 0, 256, stream);
    trsp_k<<<DOUT*DH/256, 256, 0, stream>>>(Whead, WhT);
    gemm1_f32<<<dim3(MTOT/128, DH/256), 512, 0, stream>>>(x, Win, bin, CUR);
    scan_k<<<NV/256, 256, 0, stream>>>(CUR, wrec, SPK, cnt);
    gemm2_mfma<<<dim3(MTOT/128, DOUT/128), 256, 0, stream>>>(SPK, WhT, bhead, logits);
    readout1<<<dim3(NLOG/256, 8), 256, 0, stream>>>(logits, P);
    readout2<<<NLOG/256, 256, 0, stream>>>(P, readout, cnt, srate);
}

// Round 6
// 1321.485 us; speedup vs baseline: 2.8414x; 2.8414x over previous
//
#include <hip/hip_runtime.h>
#include <hip/hip_bf16.h>
#include <stdint.h>

#define TT   512
#define BB   128
#define DIN  256
#define DH   512
#define DOUT 256
#define NV   (BB*DH)     // 65536
#define NLOG (BB*DOUT)   // 32768
#define MTOT (TT*BB)     // 65536

typedef unsigned short u16;
typedef __attribute__((ext_vector_type(8))) short bf16x8;
typedef __attribute__((ext_vector_type(4))) float f32x4;

__device__ __forceinline__ void gld_lds16(const float* g, float* l) {
    __builtin_amdgcn_global_load_lds(
        (const __attribute__((address_space(1))) void*)g,
        (__attribute__((address_space(3))) void*)l, 16, 0, 0);
}

// ========== GEMM1: CUR = X @ Win + bin, strict f32 (bitwise-np) =============
// 128x256 tile, 512 threads, 8x8/thread (acc=64 VGPR), BK=16, double-buffered
// LDS, ONE barrier per k-step. B staged via global_load_lds (no staging regs);
// A staged via one float4/thread. NO second launch_bounds arg — it imposed a
// 64/128-VGPR cap in R4/R5 and spilled the accumulator to scratch (WRITE_SIZE
// 9 GB, VALUBusy 3.5%). Per output element the math is unchanged: single
// accumulator, fmaf over k ascending (bitwise vs numpy reference).
__global__ __launch_bounds__(512) void gemm1_f32(
    const float* __restrict__ X, const float* __restrict__ Win,
    const float* __restrict__ bin, float* __restrict__ CUR)
{
    __shared__ __align__(16) float As[2][16][132];   // [buf][k][m] (+pad)
    __shared__ __align__(16) float Bs[2][16][256];   // [buf][k][n] (linear: gld_lds)
    const int bm = blockIdx.x * 128;
    const int bn = blockIdx.y * 256;
    const int t  = threadIdx.x;
    const int lane = t & 63, wid = t >> 6;        // 8 waves
    const int tx = t & 31, ty = t >> 5;           // 32(col-pairs) x 16(rows)
    const int am = t >> 2, ak = t & 3;            // A staging: row am, k-quad ak
    float acc[8][8] = {};                         // row ty*8+i, col g*64+tx*2+p
    float4 a4r;

    // prologue: stage tile 0
    a4r = *reinterpret_cast<const float4*>(&X[(size_t)(bm+am)*DIN + ak*4]);
    As[0][ak*4+0][am] = a4r.x; As[0][ak*4+1][am] = a4r.y;
    As[0][ak*4+2][am] = a4r.z; As[0][ak*4+3][am] = a4r.w;
    gld_lds16(&Win[(size_t)(wid*2+0)*DH + bn + lane*4], &Bs[0][wid*2+0][0]);
    gld_lds16(&Win[(size_t)(wid*2+1)*DH + bn + lane*4], &Bs[0][wid*2+1][0]);
    __syncthreads();

    int nb = 0;
    for (int k0 = 0; k0 < DIN; k0 += 16) {
        const int nxt = k0 + 16;
        if (nxt < DIN) {   // issue next-tile loads early (hidden under compute)
            gld_lds16(&Win[(size_t)(nxt + wid*2+0)*DH + bn + lane*4], &Bs[nb^1][wid*2+0][0]);
            gld_lds16(&Win[(size_t)(nxt + wid*2+1)*DH + bn + lane*4], &Bs[nb^1][wid*2+1][0]);
            a4r = *reinterpret_cast<const float4*>(&X[(size_t)(bm+am)*DIN + nxt + ak*4]);
        }
        #pragma unroll
        for (int kk = 0; kk < 16; ++kk) {
            float a[8], b[8];
            float4 a0 = *reinterpret_cast<const float4*>(&As[nb][kk][ty*8]);
            float4 a1 = *reinterpret_cast<const float4*>(&As[nb][kk][ty*8+4]);
            a[0]=a0.x; a[1]=a0.y; a[2]=a0.z; a[3]=a0.w;
            a[4]=a1.x; a[5]=a1.y; a[6]=a1.z; a[7]=a1.w;
            #pragma unroll
            for (int g = 0; g < 4; ++g) {   // consecutive col-pairs: 2-way = free
                float2 bp = *reinterpret_cast<const float2*>(&Bs[nb][kk][g*64 + tx*2]);
                b[g*2+0] = bp.x; b[g*2+1] = bp.y;
            }
            #pragma unroll
            for (int i = 0; i < 8; ++i)
                #pragma unroll
                for (int j = 0; j < 8; ++j)
                    acc[i][j] = fmaf(a[i], b[j], acc[i][j]);
        }
        if (nxt < DIN) {   // transpose-write A after compute
            As[nb^1][ak*4+0][am] = a4r.x; As[nb^1][ak*4+1][am] = a4r.y;
            As[nb^1][ak*4+2][am] = a4r.z; As[nb^1][ak*4+3][am] = a4r.w;
        }
        __syncthreads();   // one barrier per k-step
        nb ^= 1;
    }

    #pragma unroll
    for (int i = 0; i < 8; ++i) {
        const int row = bm + ty*8 + i;
        #pragma unroll
        for (int g = 0; g < 4; ++g) {
            const int col = bn + g*64 + tx*2;
            float2 o;
            o.x = __fadd_rn(acc[i][g*2+0], bin[col+0]);
            o.y = __fadd_rn(acc[i][g*2+1], bin[col+1]);
            *reinterpret_cast<float2*>(&CUR[(size_t)row*DH + col]) = o;
        }
    }
}

// ========== scan: strict-f32 recurrence, 16-deep load pipeline ==============
__global__ __launch_bounds__(256) void scan_k(
    const float* __restrict__ CUR, const float* __restrict__ wrec,
    u16* __restrict__ SPK, unsigned int* __restrict__ cnt)
{
    const int i = blockIdx.x*256 + threadIdx.x;
    float v = 0.0f;                       // V0 = 0
    const float w = wrec[i & (DH-1)];
    int c = 0;
    float cur[16], nxt[16];
    #pragma unroll
    for (int u = 0; u < 16; ++u) cur[u] = CUR[(size_t)u*NV + i];
    for (int t0 = 0; t0 < TT; t0 += 16) {
        if (t0 + 16 < TT) {
            #pragma unroll
            for (int u = 0; u < 16; ++u) nxt[u] = CUR[(size_t)(t0+16+u)*NV + i];
        }
        u16 sp[16];
        #pragma unroll
        for (int u = 0; u < 16; ++u) {
            const bool s = v > 1.0f;      // (V-1>0) <=> V>1 exactly in f32
            sp[u] = s ? (u16)0x3F80 : (u16)0;   // bf16 1.0 / 0.0
            c += (int)s;
            float t1 = __fmul_rn(0.9f, v);
            float t2 = __fadd_rn(t1, cur[u]);
            float t3 = __fadd_rn(t2, s ? w : 0.0f);
            v = __fsub_rn(t3, s ? 1.0f : 0.0f);
        }
        #pragma unroll
        for (int u = 0; u < 16; ++u) SPK[(size_t)(t0+u)*NV + i] = sp[u];
        #pragma unroll
        for (int u = 0; u < 16; ++u) cur[u] = nxt[u];
    }
    #pragma unroll
    for (int o = 32; o > 0; o >>= 1) c += __shfl_down(c, o, 64);
    if ((threadIdx.x & 63) == 0) atomicAdd(cnt, (unsigned int)c);
}

// ========== W_head -> bf16 transposed [DOUT][DH] ============================
__global__ __launch_bounds__(256) void trsp_k(
    const float* __restrict__ Wh, u16* __restrict__ WhT)
{
    const int id = blockIdx.x*256 + threadIdx.x;   // DOUT*DH
    const int n = id >> 9, k = id & (DH-1);
    __hip_bfloat16 h = __float2bfloat16(Wh[(size_t)k*DOUT + n]);
    WhT[id] = *reinterpret_cast<u16*>(&h);
}

// ========== GEMM2: logits = SPK @ Whead + bhead, bf16 MFMA ==================
// 128x128 tile, 4 waves (2x2), BK=32, 16x16x32 MFMA, double-buffered LDS,
// one barrier per k-step. Chunk XOR-swizzle c^(srow&3) kills frag-read
// bank conflicts. No launch_bounds min (VGPR-cap trap).
__global__ __launch_bounds__(256) void gemm2_mfma(
    const u16* __restrict__ SPK, const u16* __restrict__ WhT,
    const float* __restrict__ bh, float* __restrict__ Y)
{
    __shared__ __align__(16) u16 Ab[2][128*32];
    __shared__ __align__(16) u16 Bb[2][128*32];
    const int bm = blockIdx.x * 128;
    const int bn = blockIdx.y * 128;
    const int t = threadIdx.x;
    const int lane = t & 63, wid = t >> 6;
    const int wr = wid >> 1, wc = wid & 1;
    const int srow = t >> 1, shf = t & 1;
    uint4 va[2], vb[2];
    f32x4 acc[4][4];
    #pragma unroll
    for (int m = 0; m < 4; ++m)
        #pragma unroll
        for (int n = 0; n < 4; ++n) acc[m][n] = (f32x4){0.f,0.f,0.f,0.f};

    #define G2_LOAD(k0) do { \
        _Pragma("unroll") \
        for (int q = 0; q < 2; ++q) { \
            const int c = shf*2 + q; \
            va[q] = *reinterpret_cast<const uint4*>(&SPK[(size_t)(bm+srow)*DH + (k0) + c*8]); \
            vb[q] = *reinterpret_cast<const uint4*>(&WhT[(size_t)(bn+srow)*DH + (k0) + c*8]); \
        } \
    } while (0)
    #define G2_WRITE(nb) do { \
        _Pragma("unroll") \
        for (int q = 0; q < 2; ++q) { \
            const int c = shf*2 + q; \
            *reinterpret_cast<uint4*>(&Ab[nb][srow*32 + ((c ^ (srow&3))*8)]) = va[q]; \
            *reinterpret_cast<uint4*>(&Bb[nb][srow*32 + ((c ^ (srow&3))*8)]) = vb[q]; \
        } \
    } while (0)

    G2_LOAD(0);
    G2_WRITE(0);
    __syncthreads();

    int nb = 0;
    for (int k0 = 0; k0 < DH; k0 += 32) {
        const int nxt = k0 + 32;
        if (nxt < DH) G2_LOAD(nxt);
        const int l15 = lane & 15, lc = lane >> 4;
        bf16x8 af[4], bfr[4];
        #pragma unroll
        for (int m = 0; m < 4; ++m) {
            const int r = wr*64 + m*16 + l15;
            af[m] = *reinterpret_cast<const bf16x8*>(&Ab[nb][r*32 + ((lc ^ (r&3))*8)]);
        }
        #pragma unroll
        for (int n = 0; n < 4; ++n) {
            const int r = wc*64 + n*16 + l15;
            bfr[n] = *reinterpret_cast<const bf16x8*>(&Bb[nb][r*32 + ((lc ^ (r&3))*8)]);
        }
        #pragma unroll
        for (int m = 0; m < 4; ++m)
            #pragma unroll
            for (int n = 0; n < 4; ++n)
                acc[m][n] = __builtin_amdgcn_mfma_f32_16x16x32_bf16(
                    af[m], bfr[n], acc[m][n], 0, 0, 0);
        if (nxt < DH) G2_WRITE(nb^1);
        __syncthreads();
        nb ^= 1;
    }
    // epilogue: D col = lane&15, row = (lane>>4)*4 + r
    #pragma unroll
    for (int m = 0; m < 4; ++m)
        #pragma unroll
        for (int n = 0; n < 4; ++n) {
            const int row0 = bm + wr*64 + m*16 + (lane >> 4)*4;
            const int col  = bn + wc*64 + n*16 + (lane & 15);
            const float bv = bh[col];
            #pragma unroll
            for (int r = 0; r < 4; ++r)
                Y[(size_t)(row0 + r)*DOUT + col] = acc[m][n][r] + bv;
        }
}

// ========== readout: mean over T (two-stage, deterministic) =================
__global__ __launch_bounds__(256) void readout1(
    const float* __restrict__ L, double* __restrict__ P)
{
    const int j = blockIdx.x*256 + threadIdx.x;
    const int p = blockIdx.y;
    double s = 0.0;
    for (int u = 0; u < 64; ++u)
        s += (double)L[(size_t)(p*64 + u)*NLOG + j];
    P[(size_t)p*NLOG + j] = s;
}
__global__ __launch_bounds__(256) void readout2(
    const double* __restrict__ P, float* __restrict__ R,
    const unsigned int* __restrict__ cnt, float* __restrict__ srate)
{
    const int j = blockIdx.x*256 + threadIdx.x;
    double s = 0.0;
    #pragma unroll
    for (int p = 0; p < 8; ++p) s += P[(size_t)p*NLOG + j];
    R[j] = (float)(s / (double)TT);
    if (j == 0)
        srate[0] = (float)((double)cnt[0] / ((double)TT * (double)NV));
}

// ============================================================================
extern "C" void kernel_launch(void* const* d_in, const int* in_sizes, int n_in,
                              void* d_out, int out_size, void* d_ws, size_t ws_size,
                              hipStream_t stream)
{
    const float* x     = (const float*)d_in[0];   // [512][128][256]
    const float* Win   = (const float*)d_in[1];   // [256][512]
    const float* bin   = (const float*)d_in[2];   // [512]
    const float* wrec  = (const float*)d_in[3];   // [512]
    const float* Whead = (const float*)d_in[4];   // [512][256]
    const float* bhead = (const float*)d_in[5];   // [256]

    float* out     = (float*)d_out;
    float* readout = out;                           // 32768
    float* logits  = out + NLOG;                    // 512*32768
    float* srate   = out + NLOG + (size_t)TT*NLOG;  // 1

    char* w = (char*)d_ws;
    size_t off = 0;
    float* CUR = (float*)(w + off);  off += (size_t)TT*NV*4;      // 128 MB
    u16*   SPK = (u16*)  (w + off);  off += (size_t)TT*NV*2;      //  64 MB
    u16*   WhT = (u16*)  (w + off);  off += (size_t)DOUT*DH*2;    // 256 KB
    double* P  = (double*)(w + off); off += (size_t)8*NLOG*8;     //   2 MB
    unsigned int* cnt = (unsigned int*)(w + off);

    hipMemsetAsync(cnt, 0, 256, stream);
    trsp_k<<<DOUT*DH/256, 256, 0, stream>>>(Whead, WhT);
    gemm1_f32<<<dim3(MTOT/128, DH/256), 512, 0, stream>>>(x, Win, bin, CUR);
    scan_k<<<NV/256, 256, 0, stream>>>(CUR, wrec, SPK, cnt);
    gemm2_mfma<<<dim3(MTOT/128, DOUT/128), 256, 0, stream>>>(SPK, WhT, bhead, logits);
    readout1<<<dim3(NLOG/256, 8), 256, 0, stream>>>(logits, P);
    readout2<<<NLOG/256, 256, 0, stream>>>(P, readout, cnt, srate);
}

// Round 7
// 540.250 us; speedup vs baseline: 6.9503x; 2.4461x over previous
//
#include <hip/hip_runtime.h>
#include <hip/hip_bf16.h>
#include <stdint.h>

#define TT   512
#define BB   128
#define DIN  256
#define DH   512
#define DOUT 256
#define NV   (BB*DH)     // 65536
#define NLOG (BB*DOUT)   // 32768
#define MTOT (TT*BB)     // 65536

typedef unsigned short u16;
typedef __attribute__((ext_vector_type(8))) short bf16x8;
typedef __attribute__((ext_vector_type(4))) float f32x4;

__device__ __forceinline__ void gld_lds16(const float* g, float* l) {
    __builtin_amdgcn_global_load_lds(
        (const __attribute__((address_space(1))) void*)g,
        (__attribute__((address_space(3))) void*)l, 16, 0, 0);
}

// ========== GEMM1: CUR = X @ Win + bin, strict f32 (bitwise-np) =============
// 256 threads (4 waves: 1 wave/SIMD min -> VGPR cap 256, no spill possible for
// ~110 live), 128x128 tile, 8x8/thread (acc=64 VGPR), BK=16, double-buffered
// LDS, ONE barrier per k-step. B staged via global_load_lds into linear
// [16][128]; A reg-staged (2 float4) + transpose-written after compute.
// VGPR-cap lesson: 512-thread blocks force 2 waves/SIMD co-residency -> hard
// 128-reg cap -> R4/R5/R6 spilled. 256-thread blocks cap at 256.
// Per output element the math is unchanged: single accumulator, fmaf over k
// ascending (bitwise vs numpy reference — spikes feed back; do not alter).
__global__ __launch_bounds__(256) void gemm1_f32(
    const float* __restrict__ X, const float* __restrict__ Win,
    const float* __restrict__ bin, float* __restrict__ CUR)
{
    __shared__ __align__(16) float As[2][16][132];   // [buf][k][m] (+4 pad)
    __shared__ __align__(16) float Bs[2][16][128];   // [buf][k][n] linear (gld_lds)
    const int bm = blockIdx.x * 128;
    const int bn = blockIdx.y * 128;
    const int t  = threadIdx.x;
    const int tx = t & 15, ty = t >> 4;   // 16 col-groups x 16 row-groups
    float acc[8][8] = {};                 // [i][g*2+p]: row ty*8+i, col g*32+tx*2+p
    float4 a4s[2];

    #define G1_STAGE_B(nb_, k0_) do { \
        _Pragma("unroll") \
        for (int p = 0; p < 2; ++p) { \
            const int f = p*256 + t;              /* float4 index 0..511 */ \
            const int row = f >> 5, c4 = f & 31; \
            gld_lds16(&Win[(size_t)((k0_)+row)*DH + bn + c4*4], &Bs[nb_][row][c4*4]); \
        } \
    } while (0)
    #define G1_LOAD_A(k0_) do { \
        _Pragma("unroll") \
        for (int p = 0; p < 2; ++p) { \
            const int f = p*256 + t; \
            const int row = f >> 2, q = f & 3; \
            a4s[p] = *reinterpret_cast<const float4*>( \
                &X[(size_t)(bm+row)*DIN + (k0_) + q*4]); \
        } \
    } while (0)
    #define G1_WRITE_A(nb_) do { \
        _Pragma("unroll") \
        for (int p = 0; p < 2; ++p) { \
            const int f = p*256 + t; \
            const int row = f >> 2, q = f & 3; \
            As[nb_][q*4+0][row] = a4s[p].x; As[nb_][q*4+1][row] = a4s[p].y; \
            As[nb_][q*4+2][row] = a4s[p].z; As[nb_][q*4+3][row] = a4s[p].w; \
        } \
    } while (0)

    // prologue: stage tile 0
    G1_STAGE_B(0, 0);
    G1_LOAD_A(0);
    G1_WRITE_A(0);
    __syncthreads();                      // drains vmcnt -> B tile 0 visible

    int nb = 0;
    for (int k0 = 0; k0 < DIN; k0 += 16) {
        const int nxt = k0 + 16;
        if (nxt < DIN) {                  // issue next-tile loads under compute
            G1_STAGE_B(nb^1, nxt);
            G1_LOAD_A(nxt);
        }
        #pragma unroll
        for (int kk = 0; kk < 16; ++kk) {
            float a[8], b[8];
            float4 a0 = *reinterpret_cast<const float4*>(&As[nb][kk][ty*8]);
            float4 a1 = *reinterpret_cast<const float4*>(&As[nb][kk][ty*8+4]);
            a[0]=a0.x; a[1]=a0.y; a[2]=a0.z; a[3]=a0.w;
            a[4]=a1.x; a[5]=a1.y; a[6]=a1.z; a[7]=a1.w;
            #pragma unroll
            for (int g = 0; g < 4; ++g) {  // 16 lanes x stride-2 words: conflict-free
                float2 bp = *reinterpret_cast<const float2*>(&Bs[nb][kk][g*32 + tx*2]);
                b[g*2+0] = bp.x; b[g*2+1] = bp.y;
            }
            #pragma unroll
            for (int i = 0; i < 8; ++i)
                #pragma unroll
                for (int j = 0; j < 8; ++j)
                    acc[i][j] = fmaf(a[i], b[j], acc[i][j]);
        }
        if (nxt < DIN) G1_WRITE_A(nb^1);  // transpose-write A after compute
        __syncthreads();                  // one barrier per k-step
        nb ^= 1;
    }

    #pragma unroll
    for (int i = 0; i < 8; ++i) {
        const int row = bm + ty*8 + i;
        #pragma unroll
        for (int g = 0; g < 4; ++g) {
            const int col = bn + g*32 + tx*2;
            float2 o;
            o.x = __fadd_rn(acc[i][g*2+0], bin[col+0]);
            o.y = __fadd_rn(acc[i][g*2+1], bin[col+1]);
            *reinterpret_cast<float2*>(&CUR[(size_t)row*DH + col]) = o;
        }
    }
}

// ========== scan: strict-f32 recurrence, 16-deep load pipeline ==============
__global__ __launch_bounds__(256) void scan_k(
    const float* __restrict__ CUR, const float* __restrict__ wrec,
    u16* __restrict__ SPK, unsigned int* __restrict__ cnt)
{
    const int i = blockIdx.x*256 + threadIdx.x;
    float v = 0.0f;                       // V0 = 0
    const float w = wrec[i & (DH-1)];
    int c = 0;
    float cur[16], nxt[16];
    #pragma unroll
    for (int u = 0; u < 16; ++u) cur[u] = CUR[(size_t)u*NV + i];
    for (int t0 = 0; t0 < TT; t0 += 16) {
        if (t0 + 16 < TT) {
            #pragma unroll
            for (int u = 0; u < 16; ++u) nxt[u] = CUR[(size_t)(t0+16+u)*NV + i];
        }
        u16 sp[16];
        #pragma unroll
        for (int u = 0; u < 16; ++u) {
            const bool s = v > 1.0f;      // (V-1>0) <=> V>1 exactly in f32
            sp[u] = s ? (u16)0x3F80 : (u16)0;   // bf16 1.0 / 0.0
            c += (int)s;
            float t1 = __fmul_rn(0.9f, v);
            float t2 = __fadd_rn(t1, cur[u]);
            float t3 = __fadd_rn(t2, s ? w : 0.0f);
            v = __fsub_rn(t3, s ? 1.0f : 0.0f);
        }
        #pragma unroll
        for (int u = 0; u < 16; ++u) SPK[(size_t)(t0+u)*NV + i] = sp[u];
        #pragma unroll
        for (int u = 0; u < 16; ++u) cur[u] = nxt[u];
    }
    #pragma unroll
    for (int o = 32; o > 0; o >>= 1) c += __shfl_down(c, o, 64);
    if ((threadIdx.x & 63) == 0) atomicAdd(cnt, (unsigned int)c);
}

// ========== W_head -> bf16 transposed [DOUT][DH] ============================
__global__ __launch_bounds__(256) void trsp_k(
    const float* __restrict__ Wh, u16* __restrict__ WhT)
{
    const int id = blockIdx.x*256 + threadIdx.x;   // DOUT*DH
    const int n = id >> 9, k = id & (DH-1);
    __hip_bfloat16 h = __float2bfloat16(Wh[(size_t)k*DOUT + n]);
    WhT[id] = *reinterpret_cast<u16*>(&h);
}

// ========== GEMM2: logits = SPK @ Whead + bhead, bf16 MFMA ==================
// 128x128 tile, 4 waves (2x2), BK=32, 16x16x32 MFMA, double-buffered LDS,
// one barrier per k-step. Chunk XOR-swizzle c^(srow&3) kills frag-read
// bank conflicts.
__global__ __launch_bounds__(256) void gemm2_mfma(
    const u16* __restrict__ SPK, const u16* __restrict__ WhT,
    const float* __restrict__ bh, float* __restrict__ Y)
{
    __shared__ __align__(16) u16 Ab[2][128*32];
    __shared__ __align__(16) u16 Bb[2][128*32];
    const int bm = blockIdx.x * 128;
    const int bn = blockIdx.y * 128;
    const int t = threadIdx.x;
    const int lane = t & 63, wid = t >> 6;
    const int wr = wid >> 1, wc = wid & 1;
    const int srow = t >> 1, shf = t & 1;
    uint4 va[2], vb[2];
    f32x4 acc[4][4];
    #pragma unroll
    for (int m = 0; m < 4; ++m)
        #pragma unroll
        for (int n = 0; n < 4; ++n) acc[m][n] = (f32x4){0.f,0.f,0.f,0.f};

    #define G2_LOAD(k0) do { \
        _Pragma("unroll") \
        for (int q = 0; q < 2; ++q) { \
            const int c = shf*2 + q; \
            va[q] = *reinterpret_cast<const uint4*>(&SPK[(size_t)(bm+srow)*DH + (k0) + c*8]); \
            vb[q] = *reinterpret_cast<const uint4*>(&WhT[(size_t)(bn+srow)*DH + (k0) + c*8]); \
        } \
    } while (0)
    #define G2_WRITE(nb) do { \
        _Pragma("unroll") \
        for (int q = 0; q < 2; ++q) { \
            const int c = shf*2 + q; \
            *reinterpret_cast<uint4*>(&Ab[nb][srow*32 + ((c ^ (srow&3))*8)]) = va[q]; \
            *reinterpret_cast<uint4*>(&Bb[nb][srow*32 + ((c ^ (srow&3))*8)]) = vb[q]; \
        } \
    } while (0)

    G2_LOAD(0);
    G2_WRITE(0);
    __syncthreads();

    int nb = 0;
    for (int k0 = 0; k0 < DH; k0 += 32) {
        const int nxt = k0 + 32;
        if (nxt < DH) G2_LOAD(nxt);
        const int l15 = lane & 15, lc = lane >> 4;
        bf16x8 af[4], bfr[4];
        #pragma unroll
        for (int m = 0; m < 4; ++m) {
            const int r = wr*64 + m*16 + l15;
            af[m] = *reinterpret_cast<const bf16x8*>(&Ab[nb][r*32 + ((lc ^ (r&3))*8)]);
        }
        #pragma unroll
        for (int n = 0; n < 4; ++n) {
            const int r = wc*64 + n*16 + l15;
            bfr[n] = *reinterpret_cast<const bf16x8*>(&Bb[nb][r*32 + ((lc ^ (r&3))*8)]);
        }
        #pragma unroll
        for (int m = 0; m < 4; ++m)
            #pragma unroll
            for (int n = 0; n < 4; ++n)
                acc[m][n] = __builtin_amdgcn_mfma_f32_16x16x32_bf16(
                    af[m], bfr[n], acc[m][n], 0, 0, 0);
        if (nxt < DH) G2_WRITE(nb^1);
        __syncthreads();
        nb ^= 1;
    }
    // epilogue: D col = lane&15, row = (lane>>4)*4 + r
    #pragma unroll
    for (int m = 0; m < 4; ++m)
        #pragma unroll
        for (int n = 0; n < 4; ++n) {
            const int row0 = bm + wr*64 + m*16 + (lane >> 4)*4;
            const int col  = bn + wc*64 + n*16 + (lane & 15);
            const float bv = bh[col];
            #pragma unroll
            for (int r = 0; r < 4; ++r)
                Y[(size_t)(row0 + r)*DOUT + col] = acc[m][n][r] + bv;
        }
}

// ========== readout: mean over T (two-stage, deterministic) =================
__global__ __launch_bounds__(256) void readout1(
    const float* __restrict__ L, double* __restrict__ P)
{
    const int j = blockIdx.x*256 + threadIdx.x;
    const int p = blockIdx.y;
    double s = 0.0;
    for (int u = 0; u < 64; ++u)
        s += (double)L[(size_t)(p*64 + u)*NLOG + j];
    P[(size_t)p*NLOG + j] = s;
}
__global__ __launch_bounds__(256) void readout2(
    const double* __restrict__ P, float* __restrict__ R,
    const unsigned int* __restrict__ cnt, float* __restrict__ srate)
{
    const int j = blockIdx.x*256 + threadIdx.x;
    double s = 0.0;
    #pragma unroll
    for (int p = 0; p < 8; ++p) s += P[(size_t)p*NLOG + j];
    R[j] = (float)(s / (double)TT);
    if (j == 0)
        srate[0] = (float)((double)cnt[0] / ((double)TT * (double)NV));
}

// ============================================================================
extern "C" void kernel_launch(void* const* d_in, const int* in_sizes, int n_in,
                              void* d_out, int out_size, void* d_ws, size_t ws_size,
                              hipStream_t stream)
{
    const float* x     = (const float*)d_in[0];   // [512][128][256]
    const float* Win   = (const float*)d_in[1];   // [256][512]
    const float* bin   = (const float*)d_in[2];   // [512]
    const float* wrec  = (const float*)d_in[3];   // [512]
    const float* Whead = (const float*)d_in[4];   // [512][256]
    const float* bhead = (const float*)d_in[5];   // [256]

    float* out     = (float*)d_out;
    float* readout = out;                           // 32768
    float* logits  = out + NLOG;                    // 512*32768
    float* srate   = out + NLOG + (size_t)TT*NLOG;  // 1

    char* w = (char*)d_ws;
    size_t off = 0;
    float* CUR = (float*)(w + off);  off += (size_t)TT*NV*4;      // 128 MB
    u16*   SPK = (u16*)  (w + off);  off += (size_t)TT*NV*2;      //  64 MB
    u16*   WhT = (u16*)  (w + off);  off += (size_t)DOUT*DH*2;    // 256 KB
    double* P  = (double*)(w + off); off += (size_t)8*NLOG*8;     //   2 MB
    unsigned int* cnt = (unsigned int*)(w + off);

    hipMemsetAsync(cnt, 0, 256, stream);
    trsp_k<<<DOUT*DH/256, 256, 0, stream>>>(Whead, WhT);
    gemm1_f32<<<dim3(MTOT/128, DH/128), 256, 0, stream>>>(x, Win, bin, CUR);
    scan_k<<<NV/256, 256, 0, stream>>>(CUR, wrec, SPK, cnt);
    gemm2_mfma<<<dim3(MTOT/128, DOUT/128), 256, 0, stream>>>(SPK, WhT, bhead, logits);
    readout1<<<dim3(NLOG/256, 8), 256, 0, stream>>>(logits, P);
    readout2<<<NLOG/256, 256, 0, stream>>>(P, readout, cnt, srate);
}